// Round 8
// baseline (93.674 us; speedup 1.0000x reference)
//
#include <hip/hip_runtime.h>

namespace {

constexpr int T = 512;
constexpr int K = 4;
constexpr int G = 20000;
constexpr int EPG = 3;
constexpr int B = 512;
constexpr int BT = 4;                  // b's per slab
constexpr int NSLAB = B / BT;          // 128 (grid x, fast dim -> XCD round-robin)
constexpr int NG = 8;                  // g-splits (grid y, slow dim)
constexpr int GPB = 2560;              // g's per block
constexpr int NCHUNK = GPB / 256;      // 10
constexpr int GPAD = NG * GPB;         // 20480
constexpr int RS = 20;                 // LDS row stride in dwords (80 B)
constexpr float SLOPE = 0.01f;

__device__ __forceinline__ float lrelu(float x) { return fmaxf(x, SLOPE * x); }
__device__ __forceinline__ float dot4(float4 a, float4 b) {
  return a.x * b.x + a.y * b.y + a.z * b.z + a.w * b.w;
}

// Prep: scatter per-g metadata into 4 dense SoA float4 arrays so the hot
// kernel's record loads are perfectly dense 16B/lane (16 lines/wave-instr
// instead of ~48 for the 48B-strided w3 read).
// R0[g]=w3[g][0][:], R1[g]=w3[g][1][:], R2[g]=w3[g][2][:],
// RM[g]=(bias, off0, off1, off2) with off_e = t_e * 80 (LDS byte offset).
__global__ __launch_bounds__(256) void prep_kernel(
    const float* __restrict__ w3, const float* __restrict__ b3,
    const int* __restrict__ edge, float4* __restrict__ R0,
    float4* __restrict__ R1, float4* __restrict__ R2, float4* __restrict__ RM) {
  const int g = blockIdx.x * 256 + threadIdx.x;  // 0..GPAD-1
  float4 a = make_float4(0.f, 0.f, 0.f, 0.f), b = a, c = a, m = a;
  if (g < G) {
    const float4* wp = reinterpret_cast<const float4*>(w3 + (size_t)g * (EPG * K));
    a = wp[0];
    b = wp[1];
    c = wp[2];
    m.x = b3[g];
    m.y = __int_as_float(edge[g * EPG + 0] * (RS * 4));
    m.z = __int_as_float(edge[g * EPG + 1] * (RS * 4));
    m.w = __int_as_float(edge[g * EPG + 2] * (RS * 4));
  } else {
    m.y = m.z = m.w = __int_as_float(0);
  }
  R0[g] = a; R1[g] = b; R2[g] = c; RM[g] = m;
}

// Fused kernel. Block = (slab of BT=4 b's) x (window of 2560 g's).
// Phase 1: compute h2[t][b][k] for the slab straight into 40KB LDS.
// Phase 2: barrier-free g-loop, thread owns one g per chunk; 4 dense dwordx4
//   record loads (1-deep pipelined), 12 ds_read_b128 gather (stride-80B rows:
//   bank-quads tile all 32 banks), 4 x 256B nontemporal store segments.
__global__ __launch_bounds__(256, 4) void fused_kernel(
    const float* __restrict__ features, const float* __restrict__ w1,
    const float* __restrict__ b1, const float* __restrict__ w2,
    const float* __restrict__ b2, const float4* __restrict__ R0,
    const float4* __restrict__ R1, const float4* __restrict__ R2,
    const float4* __restrict__ RM, float* __restrict__ out) {
  __shared__ float lds[T * RS];  // 40 KB -> 4 blocks/CU, 16 waves/CU
  const int tid = threadIdx.x;
  const int b0 = blockIdx.x * BT;
  const int gbase = blockIdx.y * GPB;

  // ---- Phase 1: h2 slab -> LDS ----
#pragma unroll
  for (int half = 0; half < 2; ++half) {
    const int t = half * 256 + tid;
    const float4 W1 = reinterpret_cast<const float4*>(w1)[t];
    const float4 B1 = reinterpret_cast<const float4*>(b1)[t];
    const float4 B2 = reinterpret_cast<const float4*>(b2)[t];
    const float4* W2 = reinterpret_cast<const float4*>(w2) + t * 4;
    const float4 r0 = W2[0];
    const float4 r1 = W2[1];
    const float4 r2 = W2[2];
    const float4 r3 = W2[3];
#pragma unroll
    for (int b = 0; b < BT; ++b) {
      const float f = features[(size_t)(b0 + b) * T + t];
      const float h0 = lrelu(f * W1.x + B1.x);
      const float h1 = lrelu(f * W1.y + B1.y);
      const float h2 = lrelu(f * W1.z + B1.z);
      const float h3 = lrelu(f * W1.w + B1.w);
      float4 o;
      o.x = lrelu(B2.x + h0 * r0.x + h1 * r1.x + h2 * r2.x + h3 * r3.x);
      o.y = lrelu(B2.y + h0 * r0.y + h1 * r1.y + h2 * r2.y + h3 * r3.y);
      o.z = lrelu(B2.z + h0 * r0.z + h1 * r1.z + h2 * r2.z + h3 * r3.z);
      o.w = lrelu(B2.w + h0 * r0.w + h1 * r1.w + h2 * r2.w + h3 * r3.w);
      *reinterpret_cast<float4*>(&lds[t * RS + b * 4]) = o;
    }
  }
  __syncthreads();  // the only barrier

  const char* ldsc = reinterpret_cast<const char*>(lds);

  // ---- Phase 2 ----
  float4 pw0 = R0[gbase + tid];
  float4 pw1 = R1[gbase + tid];
  float4 pw2 = R2[gbase + tid];
  float4 pm = RM[gbase + tid];

  for (int s = 0; s < NCHUNK; ++s) {
    const float4 c0 = pw0, c1 = pw1, c2 = pw2, cm = pm;
    const int g = gbase + s * 256 + tid;
    if (s + 1 < NCHUNK) {
      const int gn = gbase + (s + 1) * 256 + tid;
      pw0 = R0[gn]; pw1 = R1[gn]; pw2 = R2[gn]; pm = RM[gn];
    }
    const int o0 = __float_as_int(cm.y);
    const int o1 = __float_as_int(cm.z);
    const int o2 = __float_as_int(cm.w);
    float a0 = cm.x, a1 = cm.x, a2 = cm.x, a3 = cm.x;
    {
      const float4 v0 = *reinterpret_cast<const float4*>(ldsc + o0);
      const float4 v1 = *reinterpret_cast<const float4*>(ldsc + o0 + 16);
      const float4 v2 = *reinterpret_cast<const float4*>(ldsc + o0 + 32);
      const float4 v3 = *reinterpret_cast<const float4*>(ldsc + o0 + 48);
      a0 += dot4(v0, c0); a1 += dot4(v1, c0); a2 += dot4(v2, c0); a3 += dot4(v3, c0);
    }
    {
      const float4 v0 = *reinterpret_cast<const float4*>(ldsc + o1);
      const float4 v1 = *reinterpret_cast<const float4*>(ldsc + o1 + 16);
      const float4 v2 = *reinterpret_cast<const float4*>(ldsc + o1 + 32);
      const float4 v3 = *reinterpret_cast<const float4*>(ldsc + o1 + 48);
      a0 += dot4(v0, c1); a1 += dot4(v1, c1); a2 += dot4(v2, c1); a3 += dot4(v3, c1);
    }
    {
      const float4 v0 = *reinterpret_cast<const float4*>(ldsc + o2);
      const float4 v1 = *reinterpret_cast<const float4*>(ldsc + o2 + 16);
      const float4 v2 = *reinterpret_cast<const float4*>(ldsc + o2 + 32);
      const float4 v3 = *reinterpret_cast<const float4*>(ldsc + o2 + 48);
      a0 += dot4(v0, c2); a1 += dot4(v1, c2); a2 += dot4(v2, c2); a3 += dot4(v3, c2);
    }
    if (g < G) {
      __builtin_nontemporal_store(a0, &out[(size_t)(b0 + 0) * G + g]);
      __builtin_nontemporal_store(a1, &out[(size_t)(b0 + 1) * G + g]);
      __builtin_nontemporal_store(a2, &out[(size_t)(b0 + 2) * G + g]);
      __builtin_nontemporal_store(a3, &out[(size_t)(b0 + 3) * G + g]);
    }
  }
}

}  // namespace

extern "C" void kernel_launch(void* const* d_in, const int* in_sizes, int n_in,
                              void* d_out, int out_size, void* d_ws, size_t ws_size,
                              hipStream_t stream) {
  const float* features = (const float*)d_in[0];
  const float* w1 = (const float*)d_in[1];
  const float* b1 = (const float*)d_in[2];
  const float* w2 = (const float*)d_in[3];
  const float* b2 = (const float*)d_in[4];
  const float* w3 = (const float*)d_in[5];
  const float* b3 = (const float*)d_in[6];
  const int* edge = (const int*)d_in[7];
  float* out = (float*)d_out;

  float4* R0 = (float4*)d_ws;            // 4 dense SoA arrays, 320 KB each
  float4* R1 = R0 + GPAD;
  float4* R2 = R1 + GPAD;
  float4* RM = R2 + GPAD;

  prep_kernel<<<GPAD / 256, 256, 0, stream>>>(w3, b3, edge, R0, R1, R2, RM);

  dim3 grid(NSLAB, NG);  // (128, 8)
  fused_kernel<<<grid, 256, 0, stream>>>(features, w1, b1, w2, b2, R0, R1, R2,
                                         RM, out);
}